// Round 7
// baseline (94.137 us; speedup 1.0000x reference)
//
#include <hip/hip_runtime.h>
#include <hip/hip_bf16.h>
#include <math.h>

// Fixed dims: B=2, T=384, C=768 -> M = 768. NH=384, HD=2. SCALE = 1/sqrt(2).
#define SCALE_QK 0.70710678118654752f
#define PSTRIDE 589824     // 768*768 (split-K partial stride, floats)

typedef __attribute__((ext_vector_type(8))) short bf16x8;   // 8 bf16 = 4 VGPRs
typedef __attribute__((ext_vector_type(4))) float floatx4;

__device__ __forceinline__ void gload16(const void* g, void* l) {
  __builtin_amdgcn_global_load_lds(
      (const __attribute__((address_space(1))) void*)g,
      (__attribute__((address_space(3))) void*)l, 16, 0, 0);
}

__device__ __forceinline__ float bf2f(unsigned short u) {
  union { float f; unsigned int i; } c; c.i = ((unsigned int)u) << 16; return c.f;
}

__device__ __forceinline__ float gelu_f(float v) {
  return 0.5f * v * (1.f + erff(v * 0.70710678118654752f));
}

struct MegaArgs {
  const float *x, *Wq, *bq, *Wp, *bp, *g1, *be1, *g2, *be2, *W1, *b1, *W2, *b2;
  __hip_bfloat16 *h1, *qkvb, *yb, *h2, *ff1b, *Tq, *Tp, *T1, *T2;
  float *x2, *part, *out;
};

// ---------------------------------------------------------------------------
// Weight transpose+convert tile: fp32 [K][N] -> bf16 [N][K], 32x32 tile.
// jobs: qkv 1728 | proj 576 | W1 2304 | W2 2304  (total 6912)
// ---------------------------------------------------------------------------
__device__ __forceinline__ void wconv_tile(int j, const MegaArgs& a, char* smem) {
  float (*t)[33] = (float(*)[33])smem;
  const float* src; __hip_bfloat16* dst; int K, N, idx;
  if (j < 1728)      { src = a.Wq; dst = a.Tq; K = 768;  N = 2304; idx = j; }
  else if (j < 2304) { src = a.Wp; dst = a.Tp; K = 768;  N = 768;  idx = j - 1728; }
  else if (j < 4608) { src = a.W1; dst = a.T1; K = 768;  N = 3072; idx = j - 2304; }
  else               { src = a.W2; dst = a.T2; K = 3072; N = 768;  idx = j - 4608; }
  int tilesN = N >> 5;
  int tk = idx / tilesN, tn = idx - tk * tilesN;
  int r = threadIdx.x >> 5, c = threadIdx.x & 31;
#pragma unroll
  for (int p = 0; p < 4; ++p)
    t[p * 8 + r][c] = src[(size_t)(tk * 32 + p * 8 + r) * N + tn * 32 + c];
  __syncthreads();
#pragma unroll
  for (int p = 0; p < 4; ++p)
    dst[(size_t)(tn * 32 + p * 8 + r) * K + tk * 32 + c] =
        __float2bfloat16(t[c][p * 8 + r]);
}

// ---------------------------------------------------------------------------
// LN row: h1 = LN(x; g1,be1). 256 threads, 3 elems each.
// ---------------------------------------------------------------------------
__device__ __forceinline__ void ln1_row(int r, const MegaArgs& a, char* smem) {
  float* red0 = (float*)smem; float* red1 = red0 + 4;
  const float* xr = a.x + (size_t)r * 768;
  __hip_bfloat16* orow = a.h1 + (size_t)r * 768;
  float vals[3]; float s = 0.f, s2 = 0.f;
#pragma unroll
  for (int p = 0; p < 3; ++p) {
    float v = xr[threadIdx.x + p * 256];
    vals[p] = v; s += v; s2 += v * v;
  }
#pragma unroll
  for (int off = 32; off > 0; off >>= 1) {
    s += __shfl_down(s, off); s2 += __shfl_down(s2, off);
  }
  int wid = threadIdx.x >> 6, lane = threadIdx.x & 63;
  if (lane == 0) { red0[wid] = s; red1[wid] = s2; }
  __syncthreads();
  if (threadIdx.x == 0) {
    red0[0] = red0[0] + red0[1] + red0[2] + red0[3];
    red1[0] = red1[0] + red1[1] + red1[2] + red1[3];
  }
  __syncthreads();
  float mean = red0[0] * (1.f / 768), var = red1[0] * (1.f / 768) - mean * mean;
  float rstd = rsqrtf(var + 1e-5f);
#pragma unroll
  for (int p = 0; p < 3; ++p) {
    int i = threadIdx.x + p * 256;
    orow[i] = __float2bfloat16((vals[p] - mean) * rstd * a.g1[i] + a.be1[i]);
  }
}

// ---------------------------------------------------------------------------
// x2 = x + (proj partial0+1 + bp); h2 = LN(x2; g2,be2). One fused pass.
// ---------------------------------------------------------------------------
__device__ __forceinline__ void proj_ln_row(int r, const MegaArgs& a, char* smem) {
  float* red0 = (float*)smem; float* red1 = red0 + 4;
  const float* xr = a.x + (size_t)r * 768;
  const float* p0 = a.part + (size_t)r * 768;
  const float* p1 = a.part + PSTRIDE + (size_t)r * 768;
  float* x2r = a.x2 + (size_t)r * 768;
  __hip_bfloat16* orow = a.h2 + (size_t)r * 768;
  float vals[3]; float s = 0.f, s2 = 0.f;
#pragma unroll
  for (int p = 0; p < 3; ++p) {
    int i = threadIdx.x + p * 256;
    float v = xr[i] + a.bp[i] + p0[i] + p1[i];
    x2r[i] = v;
    vals[p] = v; s += v; s2 += v * v;
  }
#pragma unroll
  for (int off = 32; off > 0; off >>= 1) {
    s += __shfl_down(s, off); s2 += __shfl_down(s2, off);
  }
  int wid = threadIdx.x >> 6, lane = threadIdx.x & 63;
  if (lane == 0) { red0[wid] = s; red1[wid] = s2; }
  __syncthreads();
  if (threadIdx.x == 0) {
    red0[0] = red0[0] + red0[1] + red0[2] + red0[3];
    red1[0] = red1[0] + red1[1] + red1[2] + red1[3];
  }
  __syncthreads();
  float mean = red0[0] * (1.f / 768), var = red1[0] * (1.f / 768) - mean * mean;
  float rstd = rsqrtf(var + 1e-5f);
#pragma unroll
  for (int p = 0; p < 3; ++p) {
    int i = threadIdx.x + p * 256;
    orow[i] = __float2bfloat16((vals[p] - mean) * rstd * a.g2[i] + a.be2[i]);
  }
}

// ---------------------------------------------------------------------------
// bf16 MFMA GEMM tile, m97-structure: BM=BN=128, BK=32, 4 waves (2x2), each
// wave 64x64 out via 4x4 frags of 16x16x32. 64B LDS rows -> each wave frag
// read covers a contiguous 1KB: conflict-free, NO swizzle, linear staging.
// Depth-2 pipeline, 3 LDS buffers (3 x 16KB), counted vmcnt(4).
// SPLIT: write raw fp32 partial (N=768); else bias + bf16 out.
// ---------------------------------------------------------------------------
template <int NT, bool SPLIT>
__device__ __forceinline__ void gemm_tile(
    const __hip_bfloat16* __restrict__ A, int ldA,
    const __hip_bfloat16* __restrict__ Bt, int ldB,
    const float* __restrict__ bias, void* __restrict__ outp,
    int N, int bm, int bn, int kofe, char* lds) {
  const int tid = threadIdx.x;
  const int w = tid >> 6, l = tid & 63;

  // --- staging (linear): thread tid covers LDS byte tid*16 of each 4KB half.
  // A-half0 rows 0..63, A-half1 rows 64..127 (64B = 32 bf16 per row); B same.
  const int srow = tid >> 2;            // 0..63
  const int scolb = (tid & 3) << 4;     // byte within 64B row
  const char* aSrc  = (const char*)(A  + (size_t)(bm + srow) * ldA + kofe) + scolb;
  const char* aSrc2 = aSrc + (size_t)64 * ldA * 2;
  const char* bSrc  = (const char*)(Bt + (size_t)(bn + srow) * ldB + kofe) + scolb;
  const char* bSrc2 = bSrc + (size_t)64 * ldB * 2;
  char* dW = lds + (w << 10);  // wave-uniform base; HW adds lane*16

#define STAGE(buf, t) do {                     \
    char* d_ = dW + (buf) * 16384;             \
    gload16(aSrc  + (t) * 64, d_);             \
    gload16(aSrc2 + (t) * 64, d_ + 4096);      \
    gload16(bSrc  + (t) * 64, d_ + 8192);      \
    gload16(bSrc2 + (t) * 64, d_ + 12288);     \
  } while (0)

  // --- fragment read offsets (contiguous 16B per frag; no swizzle needed)
  const int wr = w >> 1, wc = w & 1;
  const int fr = l & 15, g = l >> 4;
  int aof[4], bof[4];
#pragma unroll
  for (int i = 0; i < 4; ++i) {
    aof[i] = (wr * 64 + i * 16 + fr) * 64 + g * 16;
    bof[i] = 8192 + (wc * 64 + i * 16 + fr) * 64 + g * 16;
  }

  floatx4 acc[4][4] = {};

#define COMPUTE(bufoff) do {                                          \
    const char* base_ = lds + (bufoff);                               \
    bf16x8 av_[4], bv_[4];                                            \
    _Pragma("unroll") for (int i = 0; i < 4; ++i) {                   \
      av_[i] = *(const bf16x8*)(base_ + aof[i]);                      \
      bv_[i] = *(const bf16x8*)(base_ + bof[i]);                      \
    }                                                                 \
    _Pragma("unroll") for (int i = 0; i < 4; ++i)                     \
      _Pragma("unroll") for (int j = 0; j < 4; ++j)                   \
        acc[i][j] = __builtin_amdgcn_mfma_f32_16x16x32_bf16(          \
            av_[i], bv_[j], acc[i][j], 0, 0, 0);                      \
  } while (0)

  // prologue: stage t=0 and t=1, wait t=0, barrier
  STAGE(0, 0);
  STAGE(1, 1);
  asm volatile("s_waitcnt vmcnt(4)" ::: "memory");
  __builtin_amdgcn_s_barrier();
  asm volatile("" ::: "memory");

#pragma unroll
  for (int t = 0; t < NT; ++t) {
    if (t + 2 < NT) STAGE((t + 2) % 3, t + 2);
    COMPUTE((t % 3) * 16384);
    if (t + 1 < NT) {
      if (t + 2 < NT) {
        asm volatile("s_waitcnt vmcnt(4)" ::: "memory");
      } else {
        asm volatile("s_waitcnt vmcnt(0)" ::: "memory");
      }
      __builtin_amdgcn_s_barrier();
      asm volatile("" ::: "memory");
    }
  }
#undef STAGE
#undef COMPUTE

  // --- epilogue. C/D: col = lane&15, row = (lane>>4)*4 + reg (m89)
  const int orow0 = bm + wr * 64 + g * 4;
  const int ocol0 = bn + wc * 64 + fr;
#pragma unroll
  for (int fm = 0; fm < 4; ++fm)
#pragma unroll
    for (int fn = 0; fn < 4; ++fn) {
      int col = ocol0 + fn * 16;
      float bv = SPLIT ? 0.f : bias[col];
#pragma unroll
      for (int i = 0; i < 4; ++i) {
        int row = orow0 + fm * 16 + i;
        if (SPLIT) {
          ((float*)outp)[(size_t)row * N + col] = acc[fm][fn][i];
        } else {
          float v = acc[fm][fn][i] + bv;
          ((__hip_bfloat16*)outp)[(size_t)row * N + col] = __float2bfloat16(v);
        }
      }
    }
}

// ---------------------------------------------------------------------------
// Attention token (256 threads): rows t and 383-t (t<128). Scores over head
// axis, causal m<=n, plain exp (bounded data).
// ---------------------------------------------------------------------------
__device__ __forceinline__ void attn_row(int n, const ushort2* base,
    const float2* ks, const float2* vs, __hip_bfloat16* yrow) {
  ushort2 qu = base[n];
  float q0 = bf2f(qu.x) * SCALE_QK, q1 = bf2f(qu.y) * SCALE_QK;
  float sm = 0.f, y0 = 0.f, y1 = 0.f;
  for (int m = 0; m <= n; ++m) {
    float2 km = ks[m], vm = vs[m];
    float p = __expf(fmaf(q0, km.x, q1 * km.y));
    sm += p;
    y0 = fmaf(p, vm.x, y0);
    y1 = fmaf(p, vm.y, y1);
  }
  float inv = 1.f / sm;
  yrow[2 * n]     = __float2bfloat16(y0 * inv);
  yrow[2 * n + 1] = __float2bfloat16(y1 * inv);
}

__device__ __forceinline__ void attn_token(int r, const MegaArgs& a, char* smem) {
  float2* ks = (float2*)smem;      // 384
  float2* vs = ks + 384;           // 384
  const int t = threadIdx.x;
  const ushort2* base = (const ushort2*)(a.qkvb + (size_t)r * 2304);
  {
    ushort2 ku = base[384 + t], vu = base[768 + t];
    ks[t] = make_float2(bf2f(ku.x), bf2f(ku.y));
    vs[t] = make_float2(bf2f(vu.x), bf2f(vu.y));
    if (t < 128) {
      ushort2 ku2 = base[384 + 256 + t], vu2 = base[768 + 256 + t];
      ks[256 + t] = make_float2(bf2f(ku2.x), bf2f(ku2.y));
      vs[256 + t] = make_float2(bf2f(vu2.x), bf2f(vu2.y));
    }
  }
  __syncthreads();
  __hip_bfloat16* yrow = a.yb + (size_t)r * 768;
  attn_row(t, base, ks, vs, yrow);
  if (t < 128) attn_row(383 - t, base, ks, vs, yrow);
}

// ---------------------------------------------------------------------------
// Final reduce: out = x2 + gelu(sum4 part + b2). idx in float4 units.
// ---------------------------------------------------------------------------
__device__ __forceinline__ void p7_elem(int idx, const MegaArgs& a) {
  int i = idx * 4;
  floatx4 s = *(const floatx4*)(a.part + i);
  s += *(const floatx4*)(a.part + PSTRIDE + i);
  s += *(const floatx4*)(a.part + 2 * (size_t)PSTRIDE + i);
  s += *(const floatx4*)(a.part + 3 * (size_t)PSTRIDE + i);
  int c = i - (i / 768) * 768;
  floatx4 bv = *(const floatx4*)(a.b2 + c);
  floatx4 xv = *(const floatx4*)(a.x2 + i);
  floatx4 o;
#pragma unroll
  for (int e = 0; e < 4; ++e) o[e] = xv[e] + gelu_f(s[e] + bv[e]);
  *(floatx4*)(a.out + i) = o;
}

// ---------------------------------------------------------------------------
// Per-phase kernels.
// ---------------------------------------------------------------------------
__global__ __launch_bounds__(256) void p0_k(MegaArgs a) {   // wconv + LN1
  __shared__ __align__(16) char smem[8448];
  int j = blockIdx.x;
  if (j < 6912) wconv_tile(j, a, smem);
  else          ln1_row(j - 6912, a, smem);
}
__global__ __launch_bounds__(256, 2) void p1_k(MegaArgs a) {  // qkv GEMM
  __shared__ __align__(16) char smem[49152];
  int j = blockIdx.x;                       // 108 = 18 bn x 6 bm
  int bm = (j / 18) << 7, bn = (j % 18) << 7;
  gemm_tile<24, false>(a.h1, 768, a.Tq, 768, a.bq, a.qkvb, 2304, bm, bn, 0, smem);
}
__global__ __launch_bounds__(256) void p2_k(MegaArgs a) {   // attention
  __shared__ __align__(16) char smem[6144];
  attn_token(blockIdx.x, a, smem);
}
__global__ __launch_bounds__(256, 2) void p3_k(MegaArgs a) {  // proj split-K x2
  __shared__ __align__(16) char smem[49152];
  int j = blockIdx.x;                       // 72 = 2 z x (6x6)
  int z = j / 36, r2 = j - z * 36;
  int bm = (r2 / 6) << 7, bn = (r2 % 6) << 7;
  gemm_tile<12, true>(a.yb, 768, a.Tp, 768, nullptr,
                      a.part + (size_t)z * PSTRIDE, 768, bm, bn, z * 384, smem);
}
__global__ __launch_bounds__(256) void p4_k(MegaArgs a) {   // reduce+res+LN2
  __shared__ __align__(16) char smem[64];
  proj_ln_row(blockIdx.x, a, smem);
}
__global__ __launch_bounds__(256, 2) void p5_k(MegaArgs a) {  // ff1 GEMM
  __shared__ __align__(16) char smem[49152];
  int j = blockIdx.x;                       // 144 = 24 bn x 6 bm
  int bm = (j / 24) << 7, bn = (j % 24) << 7;
  gemm_tile<24, false>(a.h2, 768, a.T1, 768, a.b1, a.ff1b, 3072, bm, bn, 0, smem);
}
__global__ __launch_bounds__(256, 2) void p6_k(MegaArgs a) {  // ff2 split-K x4
  __shared__ __align__(16) char smem[49152];
  int j = blockIdx.x;                       // 144 = 4 z x (6x6)
  int z = j / 36, r2 = j - z * 36;
  int bm = (r2 / 6) << 7, bn = (r2 % 6) << 7;
  gemm_tile<24, true>(a.ff1b, 3072, a.T2, 3072, nullptr,
                      a.part + (size_t)z * PSTRIDE, 768, bm, bn, z * 768, smem);
}
__global__ __launch_bounds__(256) void p7_k(MegaArgs a) {   // reduce+gelu+res
  p7_elem(blockIdx.x * 256 + threadIdx.x, a);
}

// ---------------------------------------------------------------------------
extern "C" void kernel_launch(void* const* d_in, const int* in_sizes, int n_in,
                              void* d_out, int out_size, void* d_ws,
                              size_t ws_size, hipStream_t stream) {
  (void)in_sizes; (void)n_in; (void)out_size; (void)ws_size;
  MegaArgs a;
  a.x   = (const float*)d_in[0];
  a.Wq  = (const float*)d_in[1];
  a.bq  = (const float*)d_in[2];
  a.Wp  = (const float*)d_in[3];
  a.bp  = (const float*)d_in[4];
  a.g1  = (const float*)d_in[5];
  a.be1 = (const float*)d_in[6];
  a.g2  = (const float*)d_in[7];
  a.be2 = (const float*)d_in[8];
  a.W1  = (const float*)d_in[9];
  a.b1  = (const float*)d_in[10];
  a.W2  = (const float*)d_in[11];
  a.b2  = (const float*)d_in[12];

  char* p = (char*)d_ws;
  a.h1   = (__hip_bfloat16*)p; p += 768 * 768 * 2;
  a.qkvb = (__hip_bfloat16*)p; p += 768 * 2304 * 2;
  a.yb   = (__hip_bfloat16*)p; p += 768 * 768 * 2;
  a.x2   = (float*)p;          p += 768 * 768 * 4;
  a.h2   = (__hip_bfloat16*)p; p += 768 * 768 * 2;
  a.ff1b = (__hip_bfloat16*)p; p += 768 * 3072 * 2;
  a.Tq   = (__hip_bfloat16*)p; p += 2304 * 768 * 2;
  a.Tp   = (__hip_bfloat16*)p; p += 768 * 768 * 2;
  a.T1   = (__hip_bfloat16*)p; p += 3072 * 768 * 2;
  a.T2   = (__hip_bfloat16*)p; p += 768 * 3072 * 2;
  a.part = (float*)p;          p += 4 * 768 * 768 * 4;
  a.out  = (float*)d_out;

  p0_k<<<7680, 256, 0, stream>>>(a);  // weights->bf16[N][K] + LN1
  p1_k<<<108, 256, 0, stream>>>(a);   // qkv = h1 @ Tq^T + bq
  p2_k<<<768, 256, 0, stream>>>(a);   // per-token head-axis attention
  p3_k<<<72, 256, 0, stream>>>(a);    // proj split-K x2 -> part
  p4_k<<<768, 256, 0, stream>>>(a);   // x2 = x + proj + bp; h2 = LN2(x2)
  p5_k<<<144, 256, 0, stream>>>(a);   // ff1 = h2 @ T1^T + b1
  p6_k<<<144, 256, 0, stream>>>(a);   // ff2 split-K x4 -> part
  p7_k<<<576, 256, 0, stream>>>(a);   // out = x2 + gelu(sum part + b2)
}

// Round 8
// 84.473 us; speedup vs baseline: 1.1144x; 1.1144x over previous
//
#include <hip/hip_runtime.h>
#include <hip/hip_bf16.h>
#include <math.h>

// Fixed dims: B=2, T=384, C=768 -> M = 768. NH=384, HD=2. SCALE = 1/sqrt(2).
#define SCALE_QK 0.70710678118654752f
#define PSTRIDE 589824     // 768*768 (split-K partial stride, floats)

typedef __attribute__((ext_vector_type(8))) short bf16x8;   // 8 bf16 = 4 VGPRs
typedef __attribute__((ext_vector_type(4))) float floatx4;

__device__ __forceinline__ void gload16(const void* g, void* l) {
  __builtin_amdgcn_global_load_lds(
      (const __attribute__((address_space(1))) void*)g,
      (__attribute__((address_space(3))) void*)l, 16, 0, 0);
}

__device__ __forceinline__ float bf2f(unsigned short u) {
  union { float f; unsigned int i; } c; c.i = ((unsigned int)u) << 16; return c.f;
}

__device__ __forceinline__ float gelu_f(float v) {
  return 0.5f * v * (1.f + erff(v * 0.70710678118654752f));
}

struct MegaArgs {
  const float *x, *Wq, *bq, *Wp, *bp, *g1, *be1, *g2, *be2, *W1, *b1, *W2, *b2;
  __hip_bfloat16 *h1, *qkvb, *yb, *h2, *ff1b, *Tq, *Tp, *T1, *T2;
  float *x2, *part, *out;
};

// ---------------------------------------------------------------------------
// Weight transpose+convert tile: fp32 [K][N] -> bf16 [N][K], 32x32 tile.
// jobs: qkv 1728 | proj 576 | W1 2304 | W2 2304  (total 6912)
// ---------------------------------------------------------------------------
__device__ __forceinline__ void wconv_tile(int j, const MegaArgs& a, char* smem) {
  float (*t)[33] = (float(*)[33])smem;
  const float* src; __hip_bfloat16* dst; int K, N, idx;
  if (j < 1728)      { src = a.Wq; dst = a.Tq; K = 768;  N = 2304; idx = j; }
  else if (j < 2304) { src = a.Wp; dst = a.Tp; K = 768;  N = 768;  idx = j - 1728; }
  else if (j < 4608) { src = a.W1; dst = a.T1; K = 768;  N = 3072; idx = j - 2304; }
  else               { src = a.W2; dst = a.T2; K = 3072; N = 768;  idx = j - 4608; }
  int tilesN = N >> 5;
  int tk = idx / tilesN, tn = idx - tk * tilesN;
  int r = threadIdx.x >> 5, c = threadIdx.x & 31;
#pragma unroll
  for (int p = 0; p < 4; ++p)
    t[p * 8 + r][c] = src[(size_t)(tk * 32 + p * 8 + r) * N + tn * 32 + c];
  __syncthreads();
#pragma unroll
  for (int p = 0; p < 4; ++p)
    dst[(size_t)(tn * 32 + p * 8 + r) * K + tk * 32 + c] =
        __float2bfloat16(t[c][p * 8 + r]);
}

// ---------------------------------------------------------------------------
// Generic LN row: dst = LN(src; g, b) in bf16. 256 threads, 3 elems each.
// ---------------------------------------------------------------------------
__device__ __forceinline__ void ln_row(const float* __restrict__ src,
                                       const float* __restrict__ g,
                                       const float* __restrict__ b,
                                       __hip_bfloat16* __restrict__ dst,
                                       int r, char* smem) {
  float* red0 = (float*)smem; float* red1 = red0 + 4;
  const float* xr = src + (size_t)r * 768;
  __hip_bfloat16* orow = dst + (size_t)r * 768;
  float vals[3]; float s = 0.f, s2 = 0.f;
#pragma unroll
  for (int p = 0; p < 3; ++p) {
    float v = xr[threadIdx.x + p * 256];
    vals[p] = v; s += v; s2 += v * v;
  }
#pragma unroll
  for (int off = 32; off > 0; off >>= 1) {
    s += __shfl_down(s, off); s2 += __shfl_down(s2, off);
  }
  int wid = threadIdx.x >> 6, lane = threadIdx.x & 63;
  if (lane == 0) { red0[wid] = s; red1[wid] = s2; }
  __syncthreads();
  if (threadIdx.x == 0) {
    red0[0] = red0[0] + red0[1] + red0[2] + red0[3];
    red1[0] = red1[0] + red1[1] + red1[2] + red1[3];
  }
  __syncthreads();
  float mean = red0[0] * (1.f / 768), var = red1[0] * (1.f / 768) - mean * mean;
  float rstd = rsqrtf(var + 1e-5f);
#pragma unroll
  for (int p = 0; p < 3; ++p) {
    int i = threadIdx.x + p * 256;
    orow[i] = __float2bfloat16((vals[p] - mean) * rstd * g[i] + b[i]);
  }
}

// ---------------------------------------------------------------------------
// bf16 MFMA GEMM tile (round-3 proven, 3x refcheck'd). 64x64, BK=64, depth-2
// pipeline over 3 LDS buffers, counted vmcnt, XOR swizzle on source+read
// (dest linear). SPLIT: raw fp32 partial (N cols); else bias (+gelu)(+res).
// ---------------------------------------------------------------------------
template <int NT, bool GELU, bool RES, bool OUT_BF16, bool SPLIT>
__device__ __forceinline__ void gemm_tile(
    const __hip_bfloat16* __restrict__ A, int ldA,
    const __hip_bfloat16* __restrict__ Bt, int ldB,
    const float* __restrict__ bias, const float* __restrict__ res,
    void* __restrict__ outp, int N, int bm, int bn, int kofe, char* lds) {
  const int tid = threadIdx.x;
  const int w = tid >> 6, l = tid & 63;

  const int sr = (w << 3) + (l >> 3);                   // 0..31
  const int swb = ((l & 7) << 4) ^ ((l >> 3) << 4);     // byte within 128B row
  const char* a0 = (const char*)(A + (size_t)(bm + sr) * ldA + kofe) + swb;
  const char* a1 = a0 + (size_t)32 * ldA * 2;
  const char* b0 = (const char*)(Bt + (size_t)(bn + sr) * ldB + kofe) + swb;
  const char* b1 = b0 + (size_t)32 * ldB * 2;
  char* dW = lds + (w << 10);

#define STAGE(buf, t) do {                     \
    char* d_ = dW + (buf) * 16384;             \
    gload16(a0 + (t) * 128, d_);               \
    gload16(a1 + (t) * 128, d_ + 4096);        \
    gload16(b0 + (t) * 128, d_ + 8192);        \
    gload16(b1 + (t) * 128, d_ + 12288);       \
  } while (0)

  const int wr = w >> 1, wc = w & 1;
  const int fr = l & 15, g = l >> 4;
  const int fsw = (fr & 7) << 4;
  int aof[2][2], bof[2][2];
#pragma unroll
  for (int i = 0; i < 2; ++i)
#pragma unroll
    for (int kk = 0; kk < 2; ++kk) {
      aof[i][kk] = (wr * 32 + i * 16 + fr) * 128 + ((kk * 64 + g * 16) ^ fsw);
      bof[i][kk] = 8192 + (wc * 32 + i * 16 + fr) * 128 +
                   ((kk * 64 + g * 16) ^ fsw);
    }

  floatx4 acc[2][2] = {};

#define COMPUTE(bufoff) do {                                          \
    const char* base_ = lds + (bufoff);                               \
    bf16x8 av_[2][2], bv_[2][2];                                      \
    _Pragma("unroll") for (int i = 0; i < 2; ++i)                     \
      _Pragma("unroll") for (int kk = 0; kk < 2; ++kk) {              \
        av_[i][kk] = *(const bf16x8*)(base_ + aof[i][kk]);            \
        bv_[i][kk] = *(const bf16x8*)(base_ + bof[i][kk]);            \
      }                                                               \
    _Pragma("unroll") for (int kk = 0; kk < 2; ++kk)                  \
      _Pragma("unroll") for (int i = 0; i < 2; ++i)                   \
        _Pragma("unroll") for (int j = 0; j < 2; ++j)                 \
          acc[i][j] = __builtin_amdgcn_mfma_f32_16x16x32_bf16(        \
              av_[i][kk], bv_[j][kk], acc[i][j], 0, 0, 0);            \
  } while (0)

  STAGE(0, 0);
  STAGE(1, 1);
  asm volatile("s_waitcnt vmcnt(4)" ::: "memory");
  __builtin_amdgcn_s_barrier();
  asm volatile("" ::: "memory");

#pragma unroll
  for (int t = 0; t < NT; ++t) {
    if (t + 2 < NT) STAGE((t + 2) % 3, t + 2);
    COMPUTE((t % 3) * 16384);
    if (t + 1 < NT) {
      if (t + 2 < NT) {
        asm volatile("s_waitcnt vmcnt(4)" ::: "memory");
      } else {
        asm volatile("s_waitcnt vmcnt(0)" ::: "memory");
      }
      __builtin_amdgcn_s_barrier();
      asm volatile("" ::: "memory");
    }
  }
#undef STAGE
#undef COMPUTE

  // C/D: col = lane&15, row = (lane>>4)*4 + reg (m89)
  const int orow0 = bm + wr * 32 + g * 4;
  const int ocol0 = bn + wc * 32 + fr;
#pragma unroll
  for (int fm = 0; fm < 2; ++fm)
#pragma unroll
    for (int fn = 0; fn < 2; ++fn) {
      int col = ocol0 + fn * 16;
      float bv = SPLIT ? 0.f : bias[col];
#pragma unroll
      for (int i = 0; i < 4; ++i) {
        int row = orow0 + fm * 16 + i;
        if (SPLIT) {
          ((float*)outp)[(size_t)row * N + col] = acc[fm][fn][i];
        } else {
          float v = acc[fm][fn][i] + bv;
          if (GELU) v = gelu_f(v);
          if (RES) v += res[(size_t)row * N + col];
          if (OUT_BF16)
            ((__hip_bfloat16*)outp)[(size_t)row * N + col] = __float2bfloat16(v);
          else
            ((float*)outp)[(size_t)row * N + col] = v;
        }
      }
    }
}

// ---------------------------------------------------------------------------
// Attention token (256 threads): rows t and 383-t (t<128) -> balanced 385
// iters/thread. Scores over head axis, causal m<=n, plain exp (bounded data).
// ---------------------------------------------------------------------------
__device__ __forceinline__ void attn_row(int n, const ushort2* base,
    const float2* ks, const float2* vs, __hip_bfloat16* yrow) {
  ushort2 qu = base[n];
  float q0 = bf2f(qu.x) * SCALE_QK, q1 = bf2f(qu.y) * SCALE_QK;
  float sm = 0.f, y0 = 0.f, y1 = 0.f;
  for (int m = 0; m <= n; ++m) {
    float2 km = ks[m], vm = vs[m];
    float p = __expf(fmaf(q0, km.x, q1 * km.y));
    sm += p;
    y0 = fmaf(p, vm.x, y0);
    y1 = fmaf(p, vm.y, y1);
  }
  float inv = 1.f / sm;
  yrow[2 * n]     = __float2bfloat16(y0 * inv);
  yrow[2 * n + 1] = __float2bfloat16(y1 * inv);
}

__device__ __forceinline__ void attn_token(int r, const MegaArgs& a, char* smem) {
  float2* ks = (float2*)smem;      // 384
  float2* vs = ks + 384;           // 384
  const int t = threadIdx.x;
  const ushort2* base = (const ushort2*)(a.qkvb + (size_t)r * 2304);
  {
    ushort2 ku = base[384 + t], vu = base[768 + t];
    ks[t] = make_float2(bf2f(ku.x), bf2f(ku.y));
    vs[t] = make_float2(bf2f(vu.x), bf2f(vu.y));
    if (t < 128) {
      ushort2 ku2 = base[384 + 256 + t], vu2 = base[768 + 256 + t];
      ks[256 + t] = make_float2(bf2f(ku2.x), bf2f(ku2.y));
      vs[256 + t] = make_float2(bf2f(vu2.x), bf2f(vu2.y));
    }
  }
  __syncthreads();
  __hip_bfloat16* yrow = a.yb + (size_t)r * 768;
  attn_row(t, base, ks, vs, yrow);
  if (t < 128) attn_row(383 - t, base, ks, vs, yrow);
}

// ---------------------------------------------------------------------------
// Final reduce: out = x2 + gelu(sum4 part + b2). idx in float4 units.
// ---------------------------------------------------------------------------
__device__ __forceinline__ void p7_elem(int idx, const MegaArgs& a) {
  int i = idx * 4;
  floatx4 s = *(const floatx4*)(a.part + i);
  s += *(const floatx4*)(a.part + PSTRIDE + i);
  s += *(const floatx4*)(a.part + 2 * (size_t)PSTRIDE + i);
  s += *(const floatx4*)(a.part + 3 * (size_t)PSTRIDE + i);
  int c = i - (i / 768) * 768;
  floatx4 bv = *(const floatx4*)(a.b2 + c);
  floatx4 xv = *(const floatx4*)(a.x2 + i);
  floatx4 o;
#pragma unroll
  for (int e = 0; e < 4; ++e) o[e] = xv[e] + gelu_f(s[e] + bv[e]);
  *(floatx4*)(a.out + i) = o;
}

// ---------------------------------------------------------------------------
// Per-phase kernels (round-3 structure: 64^2 tiles, direct proj+RES).
// ---------------------------------------------------------------------------
__global__ __launch_bounds__(256) void p0_k(MegaArgs a) {   // wconv + LN1
  __shared__ __align__(16) char smem[8448];
  int j = blockIdx.x;
  if (j < 6912) wconv_tile(j, a, smem);
  else          ln_row(a.x, a.g1, a.be1, a.h1, j - 6912, smem);
}
__global__ __launch_bounds__(256) void p1_k(MegaArgs a) {   // qkv GEMM (432)
  __shared__ __align__(16) char smem[49152];
  int j = blockIdx.x;
  int bm = (j / 36) << 6, bn = (j % 36) << 6;
  gemm_tile<12, false, false, true, false>(
      a.h1, 768, a.Tq, 768, a.bq, nullptr, a.qkvb, 2304, bm, bn, 0, smem);
}
__global__ __launch_bounds__(256) void p2_k(MegaArgs a) {   // attention (768)
  __shared__ __align__(16) char smem[6144];
  attn_token(blockIdx.x, a, smem);
}
__global__ __launch_bounds__(256) void p3_k(MegaArgs a) {   // proj+res (144)
  __shared__ __align__(16) char smem[49152];
  int j = blockIdx.x;
  int bm = (j / 12) << 6, bn = (j % 12) << 6;
  gemm_tile<12, false, true, false, false>(
      a.yb, 768, a.Tp, 768, a.bp, a.x, a.x2, 768, bm, bn, 0, smem);
}
__global__ __launch_bounds__(256) void p4_k(MegaArgs a) {   // LN2 (768)
  __shared__ __align__(16) char smem[64];
  ln_row(a.x2, a.g2, a.be2, a.h2, blockIdx.x, smem);
}
__global__ __launch_bounds__(256) void p5_k(MegaArgs a) {   // ff1 GEMM (576)
  __shared__ __align__(16) char smem[49152];
  int j = blockIdx.x;
  int bm = (j / 48) << 6, bn = (j % 48) << 6;
  gemm_tile<12, false, false, true, false>(
      a.h2, 768, a.T1, 768, a.b1, nullptr, a.ff1b, 3072, bm, bn, 0, smem);
}
__global__ __launch_bounds__(256) void p6_k(MegaArgs a) {   // ff2 splitx4 (576)
  __shared__ __align__(16) char smem[49152];
  int j = blockIdx.x;
  int z = j / 144, r2 = j - z * 144;
  int bm = (r2 / 12) << 6, bn = (r2 % 12) << 6;
  gemm_tile<12, false, false, false, true>(
      a.ff1b, 3072, a.T2, 3072, nullptr, nullptr,
      a.part + (size_t)z * PSTRIDE, 768, bm, bn, z * 768, smem);
}
__global__ __launch_bounds__(256) void p7_k(MegaArgs a) {   // reduce+gelu+res
  p7_elem(blockIdx.x * 256 + threadIdx.x, a);
}

// ---------------------------------------------------------------------------
extern "C" void kernel_launch(void* const* d_in, const int* in_sizes, int n_in,
                              void* d_out, int out_size, void* d_ws,
                              size_t ws_size, hipStream_t stream) {
  (void)in_sizes; (void)n_in; (void)out_size; (void)ws_size;
  MegaArgs a;
  a.x   = (const float*)d_in[0];
  a.Wq  = (const float*)d_in[1];
  a.bq  = (const float*)d_in[2];
  a.Wp  = (const float*)d_in[3];
  a.bp  = (const float*)d_in[4];
  a.g1  = (const float*)d_in[5];
  a.be1 = (const float*)d_in[6];
  a.g2  = (const float*)d_in[7];
  a.be2 = (const float*)d_in[8];
  a.W1  = (const float*)d_in[9];
  a.b1  = (const float*)d_in[10];
  a.W2  = (const float*)d_in[11];
  a.b2  = (const float*)d_in[12];

  char* p = (char*)d_ws;
  a.h1   = (__hip_bfloat16*)p; p += 768 * 768 * 2;
  a.qkvb = (__hip_bfloat16*)p; p += 768 * 2304 * 2;
  a.yb   = (__hip_bfloat16*)p; p += 768 * 768 * 2;
  a.x2   = (float*)p;          p += 768 * 768 * 4;
  a.h2   = (__hip_bfloat16*)p; p += 768 * 768 * 2;
  a.ff1b = (__hip_bfloat16*)p; p += 768 * 3072 * 2;
  a.Tq   = (__hip_bfloat16*)p; p += 2304 * 768 * 2;
  a.Tp   = (__hip_bfloat16*)p; p += 768 * 768 * 2;
  a.T1   = (__hip_bfloat16*)p; p += 3072 * 768 * 2;
  a.T2   = (__hip_bfloat16*)p; p += 768 * 3072 * 2;
  a.part = (float*)p;          p += 4 * 768 * 768 * 4;
  a.out  = (float*)d_out;

  p0_k<<<7680, 256, 0, stream>>>(a);  // weights->bf16[N][K] + LN1
  p1_k<<<432, 256, 0, stream>>>(a);   // qkv = h1 @ Tq^T + bq
  p2_k<<<768, 256, 0, stream>>>(a);   // per-token head-axis attention
  p3_k<<<144, 256, 0, stream>>>(a);   // x2 = x + y @ Tp^T + bp
  p4_k<<<768, 256, 0, stream>>>(a);   // h2 = LN2(x2)
  p5_k<<<576, 256, 0, stream>>>(a);   // ff1 = h2 @ T1^T + b1
  p6_k<<<576, 256, 0, stream>>>(a);   // ff2 split-K x4 -> part
  p7_k<<<576, 256, 0, stream>>>(a);   // out = x2 + gelu(sum part + b2)
}